// Round 12
// baseline (6290.553 us; speedup 1.0000x reference)
//
#include <hip/hip_runtime.h>
#include <cstdint>
#include <cstddef>

#define BATCH   8
#define NPTS    16384
#define CFEAT   64
#define NPOINT  2048
#define NSAMPLE 32
#define DIN     124
#define D1      128
#define D2      128
#define D3      256
#define LN_EPS  1e-5f

#define PTS16(F) F(0) F(1) F(2) F(3) F(4) F(5) F(6) F(7) \
                 F(8) F(9) F(10) F(11) F(12) F(13) F(14) F(15)

// ---------------------------------------------------------------------------
// Kernel 1: brute-force FPS, 2-barrier step (r12).
// r11 compute core (1024 thr, 16 pts/thread, coords in 48 asm-pinned regs,
// float4-packed LDS dists, value-only f32 argmax). r11's counters showed the
// serial tail (stage2 + critical-path rescan + 3 barriers + cbuf round-trip)
// cost ~3400 cyc/step vs ~1540 compute. Restructure:
//   - per-wave: lanes with mybest==wmax rescan + atomicMax the packed
//     (valbits<<32 | ~idx) u64 BEFORE any barrier (parallel across waves;
//     u64 max == value desc, then smallest original idx -> bit-identical
//     selections).
//   - B1 -> all threads read s_packed, decode widx, load winner coords from
//     global X[3*widx] (12B broadcast, L2-resident, bit-identical bytes;
//     latency hidden behind B2). No cbuf, no owner phase, no B3.
//   - s_packed double-buffered by step parity; off-slot reset sits between
//     B1 and B2 (barrier-separated from last reader and next writer).
// Exact reference f32 math: __fsub/__fmul/__fadd (no contraction), fminf.
// ---------------------------------------------------------------------------
__attribute__((amdgpu_waves_per_eu(4, 4)))
__global__ __launch_bounds__(1024) void fps_kernel(
    const float* __restrict__ xyz, int* __restrict__ fps_idx,
    float* __restrict__ new_xyz)
{
  const int b = blockIdx.x;
  const int t = threadIdx.x;
  const float* X = xyz + (size_t)b * NPTS * 3;

  __shared__ float4 s_mind4[4][1024];            // 64 KB, pack p = dists i=4p..4p+3
  __shared__ unsigned long long s_packed[2];     // (g_bits<<32)|~origidx, per parity

#define DECLP(i) float px##i, py##i, pz##i;
  PTS16(DECLP)
#undef DECLP

#define LOADP(i) { int j = t + (i << 10);  \
    px##i = X[3 * j + 0];                  \
    py##i = X[3 * j + 1];                  \
    pz##i = X[3 * j + 2]; }
  PTS16(LOADP)
#undef LOADP
  s_mind4[0][t] = make_float4(1e10f, 1e10f, 1e10f, 1e10f);
  s_mind4[1][t] = make_float4(1e10f, 1e10f, 1e10f, 1e10f);
  s_mind4[2][t] = make_float4(1e10f, 1e10f, 1e10f, 1e10f);
  s_mind4[3][t] = make_float4(1e10f, 1e10f, 1e10f, 1e10f);

  if (t == 0) { s_packed[0] = 0ull; s_packed[1] = 0ull; }
  int   far = 0;
  float cx = X[0], cy = X[1], cz = X[2];   // broadcast load, all threads
  __syncthreads();

  for (int s = 0; s < NPOINT; ++s) {
    if (t == 0) {
      fps_idx[b * NPOINT + s] = far;
      float* o = new_xyz + ((size_t)b * NPOINT + s) * 3;
      o[0] = cx; o[1] = cy; o[2] = cz;
    }
    if (s == NPOINT - 1) break;

    // pin coords in VGPRs (blocks spill/remat; r9/r11-proven)
    asm volatile("" : "+v"(px0), "+v"(px1), "+v"(px2), "+v"(px3),
                      "+v"(px4), "+v"(px5), "+v"(px6), "+v"(px7),
                      "+v"(px8), "+v"(px9), "+v"(px10), "+v"(px11),
                      "+v"(px12), "+v"(px13), "+v"(px14), "+v"(px15));
    asm volatile("" : "+v"(py0), "+v"(py1), "+v"(py2), "+v"(py3),
                      "+v"(py4), "+v"(py5), "+v"(py6), "+v"(py7),
                      "+v"(py8), "+v"(py9), "+v"(py10), "+v"(py11),
                      "+v"(py12), "+v"(py13), "+v"(py14), "+v"(py15));
    asm volatile("" : "+v"(pz0), "+v"(pz1), "+v"(pz2), "+v"(pz3),
                      "+v"(pz4), "+v"(pz5), "+v"(pz6), "+v"(pz7),
                      "+v"(pz8), "+v"(pz9), "+v"(pz10), "+v"(pz11),
                      "+v"(pz12), "+v"(pz13), "+v"(pz14), "+v"(pz15));

    float mybest = -1.0f;
#define DIST(i) ({                                                       \
    float dx_ = __fsub_rn(px##i, cx);                                    \
    float dy_ = __fsub_rn(py##i, cy);                                    \
    float dz_ = __fsub_rn(pz##i, cz);                                    \
    __fadd_rn(__fadd_rn(__fmul_rn(dx_, dx_), __fmul_rn(dy_, dy_)),       \
              __fmul_rn(dz_, dz_)); })
#define PACKSTEP(p, i0, i1, i2, i3) {                                    \
    float4 dv = s_mind4[p][t];                                           \
    dv.x = fminf(dv.x, DIST(i0));                                        \
    dv.y = fminf(dv.y, DIST(i1));                                        \
    dv.z = fminf(dv.z, DIST(i2));                                        \
    dv.w = fminf(dv.w, DIST(i3));                                        \
    s_mind4[p][t] = dv;                                                  \
    mybest = fmaxf(mybest, fmaxf(fmaxf(dv.x, dv.y), fmaxf(dv.z, dv.w))); }
    PACKSTEP(0, 0, 1, 2, 3)
    PACKSTEP(1, 4, 5, 6, 7)
    PACKSTEP(2, 8, 9, 10, 11)
    PACKSTEP(3, 12, 13, 14, 15)
#undef PACKSTEP
#undef DIST

    // f32-only wave max
    float wmax = mybest;
#pragma unroll
    for (int off = 32; off >= 1; off >>= 1)
      wmax = fmaxf(wmax, __shfl_xor(wmax, off));

    // per-wave submit (pre-barrier, parallel): lanes at the wave max rescan
    // their packs (descending-overwrite -> smallest i) and atomicMax
    if (mybest == wmax) {
      int kk = 16;
#pragma unroll
      for (int p = 3; p >= 0; --p) {
        float4 dv = s_mind4[p][t];
        if (dv.w == mybest) kk = 4 * p + 3;
        if (dv.z == mybest) kk = 4 * p + 2;
        if (dv.y == mybest) kk = 4 * p + 1;
        if (dv.x == mybest) kk = 4 * p + 0;
      }
      unsigned idx = (unsigned)(t + (kk << 10));
      unsigned long long pk =
          ((unsigned long long)__float_as_uint(mybest) << 32) |
          (unsigned)(~idx);
      atomicMax(&s_packed[s & 1], pk);
    }
    __syncthreads();   // B1: all submissions visible

    unsigned long long gp = s_packed[s & 1];
    if (t == 0) s_packed[(s & 1) ^ 1] = 0ull;   // reset off-slot (barrier-fenced both sides)
    int widx = (int)(~(unsigned)(gp & 0xffffffffull)) & 0x3fff;
    far = widx;
    const float* Wp = X + 3 * (size_t)widx;     // broadcast, L1/L2-resident
    float ncx = Wp[0], ncy = Wp[1], ncz = Wp[2];
    __syncthreads();   // B2: reset fenced from next step's atomics; load hides here
    cx = ncx; cy = ncy; cz = ncz;
  }
}

// ---------------------------------------------------------------------------
// Kernel 2: exact 32-NN per centroid (r7/r9/r11 version, passing).
// ---------------------------------------------------------------------------
__attribute__((amdgpu_waves_per_eu(2, 2)))
__global__ __launch_bounds__(256) void knn_kernel(
    const float* __restrict__ xyz, const float* __restrict__ new_xyz,
    int* __restrict__ knn_idx)
{
  const int lane = threadIdx.x & 63;
  const int wid  = threadIdx.x >> 6;
  const int gidbase = blockIdx.x * 64 + wid * 16;
  const int b = gidbase / NPOINT;
  const float* X = xyz + (size_t)b * NPTS * 3;

  float cx[16], cy[16], cz[16];
#pragma unroll
  for (int c = 0; c < 16; ++c) {
    const float* p = new_xyz + (size_t)(gidbase + c) * 3;
    cx[c] = p[0]; cy[c] = p[1]; cz[c] = p[2];
  }

  float qd[16]; int qi[16]; float T[16];
#pragma unroll
  for (int c = 0; c < 16; ++c) { qd[c] = 3.4e38f; qi[c] = 0; T[c] = 3.4e38f; }

  for (int base = 0; base < NPTS; base += 64) {
    const int j = base + lane;
    const float x = X[3 * j + 0];
    const float y = X[3 * j + 1];
    const float z = X[3 * j + 2];
#pragma unroll
    for (int c = 0; c < 16; ++c) {
      float dx = __fsub_rn(x, cx[c]);
      float dy = __fsub_rn(y, cy[c]);
      float dz = __fsub_rn(z, cz[c]);
      float v  = __fadd_rn(__fadd_rn(__fmul_rn(dx, dx), __fmul_rn(dy, dy)),
                           __fmul_rn(dz, dz));
      unsigned long long m = __ballot(v < T[c]);
      while (m) {
        int bit = __ffsll(m) - 1;
        m &= m - 1;
        float vb = __shfl(v, bit);
        if (vb < T[c]) {
          int   jb = base + bit;
          float du = __shfl_up(qd[c], 1);
          int   iu = __shfl_up(qi[c], 1);
          bool c2 = (lane > 0) && (vb < du);
          bool c1 = vb < qd[c];
          qd[c] = c2 ? du : (c1 ? vb : qd[c]);
          qi[c] = c2 ? iu : (c1 ? jb : qi[c]);
          T[c] = __shfl(qd[c], 31);
        }
      }
    }
  }
#pragma unroll
  for (int c = 0; c < 16; ++c) {
    if (lane < 32) knn_idx[(size_t)(gidbase + c) * NSAMPLE + lane] = qi[c];
  }
}

// ---------------------------------------------------------------------------
// Kernel 3: gather + NeRF encoding + 3-layer MLP (f32) + max over k
// (r7/r9/r11 version, passing).
// ---------------------------------------------------------------------------
__attribute__((amdgpu_waves_per_eu(4, 4)))
__global__ __launch_bounds__(128) void mlp_kernel(
    const float* __restrict__ xyz, const float* __restrict__ features,
    const float* __restrict__ new_xyz, const int* __restrict__ knn_idx,
    const float* __restrict__ W1, const float* __restrict__ b1,
    const float* __restrict__ g1, const float* __restrict__ be1,
    const float* __restrict__ W2, const float* __restrict__ b2,
    const float* __restrict__ g2, const float* __restrict__ be2,
    const float* __restrict__ W3, const float* __restrict__ b3,
    float* __restrict__ out)
{
  const int g = blockIdx.x;
  const int b = g / NPOINT;
  const int t = threadIdx.x;

  __shared__ float bufT[128 * 36];
  __shared__ int   ki[32];
  __shared__ float cen[3];
  __shared__ float red[32][4][2];
  __shared__ float lnp[32][2];

  if (t < 32) ki[t] = knn_idx[(size_t)g * NSAMPLE + t];
  if (t < 3)  cen[t] = new_xyz[(size_t)g * 3 + t];
  __syncthreads();

  {
    int r = t & 31, cs = (t >> 5) << 4;
    const float* frow = features + ((size_t)b * NPTS + ki[r]) * CFEAT + cs;
#pragma unroll
    for (int u = 0; u < 4; ++u) {
      float4 f = *(const float4*)(frow + 4 * u);
      bufT[(cs + 4 * u + 0) * 36 + r] = f.x;
      bufT[(cs + 4 * u + 1) * 36 + r] = f.y;
      bufT[(cs + 4 * u + 2) * 36 + r] = f.z;
      bufT[(cs + 4 * u + 3) * 36 + r] = f.w;
    }
  }
  if (t < 32) {
    const float* p = xyz + ((size_t)b * NPTS + ki[t]) * 3;
    float rx = p[0] - cen[0];
    float ry = p[1] - cen[1];
    float rz = p[2] - cen[2];
#pragma unroll
    for (int l = 0; l < 10; ++l) {
      float sc = (float)(1 << l);
      float ax = rx * sc, ay = ry * sc, az = rz * sc;
      int base = (64 + l * 6) * 36 + t;
      bufT[base + 0 * 36] = __sinf(ax);
      bufT[base + 1 * 36] = __sinf(ay);
      bufT[base + 2 * 36] = __sinf(az);
      bufT[base + 3 * 36] = __cosf(ax);
      bufT[base + 4 * 36] = __cosf(ay);
      bufT[base + 5 * 36] = __cosf(az);
    }
  }
  __syncthreads();

  float acc[32];

  {
    float bias = b1[t];
#pragma unroll
    for (int r = 0; r < 32; ++r) acc[r] = bias;
    for (int i = 0; i < DIN; ++i) {
      float w = W1[i * D1 + t];
      const float* hr = &bufT[i * 36];
#pragma unroll
      for (int r = 0; r < 32; ++r) acc[r] = fmaf(hr[r], w, acc[r]);
    }
  }
  {
    __syncthreads();
#pragma unroll
    for (int r = 0; r < 32; ++r) bufT[t * 36 + r] = acc[r];
    __syncthreads();
    {
      int r = t & 31, seg = t >> 5;
      float s = 0.f, ss = 0.f;
#pragma unroll
      for (int u = 0; u < 32; ++u) {
        float v = bufT[(seg * 32 + u) * 36 + r];
        s += v; ss = fmaf(v, v, ss);
      }
      red[r][seg][0] = s; red[r][seg][1] = ss;
    }
    __syncthreads();
    if (t < 32) {
      float s  = red[t][0][0] + red[t][1][0] + red[t][2][0] + red[t][3][0];
      float ss = red[t][0][1] + red[t][1][1] + red[t][2][1] + red[t][3][1];
      float m  = s * (1.0f / D1);
      float var = ss * (1.0f / D1) - m * m;
      lnp[t][0] = m;
      lnp[t][1] = rsqrtf(var + LN_EPS);
    }
    __syncthreads();
    float gg = g1[t], bb = be1[t];
#pragma unroll
    for (int r = 0; r < 32; ++r) {
      float v = (acc[r] - lnp[r][0]) * lnp[r][1];
      v = fmaf(v, gg, bb);
      bufT[t * 36 + r] = fmaxf(v, 0.f);
    }
    __syncthreads();
  }

  {
    float bias = b2[t];
#pragma unroll
    for (int r = 0; r < 32; ++r) acc[r] = bias;
    for (int i = 0; i < D1; ++i) {
      float w = W2[i * D2 + t];
      const float* hr = &bufT[i * 36];
#pragma unroll
      for (int r = 0; r < 32; ++r) acc[r] = fmaf(hr[r], w, acc[r]);
    }
  }
  {
    __syncthreads();
#pragma unroll
    for (int r = 0; r < 32; ++r) bufT[t * 36 + r] = acc[r];
    __syncthreads();
    {
      int r = t & 31, seg = t >> 5;
      float s = 0.f, ss = 0.f;
#pragma unroll
      for (int u = 0; u < 32; ++u) {
        float v = bufT[(seg * 32 + u) * 36 + r];
        s += v; ss = fmaf(v, v, ss);
      }
      red[r][seg][0] = s; red[r][seg][1] = ss;
    }
    __syncthreads();
    if (t < 32) {
      float s  = red[t][0][0] + red[t][1][0] + red[t][2][0] + red[t][3][0];
      float ss = red[t][0][1] + red[t][1][1] + red[t][2][1] + red[t][3][1];
      float m  = s * (1.0f / D2);
      float var = ss * (1.0f / D2) - m * m;
      lnp[t][0] = m;
      lnp[t][1] = rsqrtf(var + LN_EPS);
    }
    __syncthreads();
    float gg = g2[t], bb = be2[t];
#pragma unroll
    for (int r = 0; r < 32; ++r) {
      float v = (acc[r] - lnp[r][0]) * lnp[r][1];
      v = fmaf(v, gg, bb);
      bufT[t * 36 + r] = fmaxf(v, 0.f);
    }
    __syncthreads();
  }

  {
    float a0[32], a1[32];
    float bias0 = b3[t], bias1 = b3[t + 128];
#pragma unroll
    for (int r = 0; r < 32; ++r) { a0[r] = bias0; a1[r] = bias1; }
    for (int i = 0; i < D2; ++i) {
      float w0 = W3[i * D3 + t];
      float w1 = W3[i * D3 + t + 128];
      const float* hr = &bufT[i * 36];
#pragma unroll
      for (int r = 0; r < 32; ++r) {
        a0[r] = fmaf(hr[r], w0, a0[r]);
        a1[r] = fmaf(hr[r], w1, a1[r]);
      }
    }
    float m0 = a0[0], m1 = a1[0];
#pragma unroll
    for (int r = 1; r < 32; ++r) { m0 = fmaxf(m0, a0[r]); m1 = fmaxf(m1, a1[r]); }
    float* of = out + (size_t)g * D3;
    of[t] = m0;
    of[t + 128] = m1;
  }
}

// ---------------------------------------------------------------------------
extern "C" void kernel_launch(void* const* d_in, const int* in_sizes, int n_in,
                              void* d_out, int out_size, void* d_ws, size_t ws_size,
                              hipStream_t stream) {
  const float* xyz      = (const float*)d_in[0];
  const float* features = (const float*)d_in[1];
  const float* W1  = (const float*)d_in[2];
  const float* b1  = (const float*)d_in[3];
  const float* g1  = (const float*)d_in[4];
  const float* be1 = (const float*)d_in[5];
  const float* W2  = (const float*)d_in[6];
  const float* b2  = (const float*)d_in[7];
  const float* g2  = (const float*)d_in[8];
  const float* be2 = (const float*)d_in[9];
  const float* W3  = (const float*)d_in[10];
  const float* b3  = (const float*)d_in[11];

  float* new_xyz  = (float*)d_out;
  float* new_feat = (float*)d_out + (size_t)BATCH * NPOINT * 3;

  int* fps_idx = (int*)d_ws;
  int* knn_idx = fps_idx + BATCH * NPOINT;

  fps_kernel<<<dim3(BATCH), dim3(1024), 0, stream>>>(xyz, fps_idx, new_xyz);
  knn_kernel<<<dim3((BATCH * NPOINT) / 64), dim3(256), 0, stream>>>(xyz, new_xyz, knn_idx);
  mlp_kernel<<<dim3(BATCH * NPOINT), dim3(128), 0, stream>>>(
      xyz, features, new_xyz, knn_idx,
      W1, b1, g1, be1, W2, b2, g2, be2, W3, b3, new_feat);
}

// Round 13
// 5747.573 us; speedup vs baseline: 1.0945x; 1.0945x over previous
//
#include <hip/hip_runtime.h>
#include <cstdint>
#include <cstddef>

#define BATCH   8
#define NPTS    16384
#define CFEAT   64
#define NPOINT  2048
#define NSAMPLE 32
#define DIN     124
#define D1      128
#define D2      128
#define D3      256
#define LN_EPS  1e-5f

#define PTS16(F) F(0) F(1) F(2) F(3) F(4) F(5) F(6) F(7) \
                 F(8) F(9) F(10) F(11) F(12) F(13) F(14) F(15)

// ---------------------------------------------------------------------------
// Kernel 1: brute-force FPS — EXACT r11 (best measured: 4240 us).
// 1024 thr, 16 pts/thread, coords in 48 asm-pinned regs, float4-packed LDS
// dists, value-only f32 argmax, stage2 redundant, winner rescan + packed-u64
// atomic tie-break (smallest original index), owner writes cbuf. 3 barriers.
// Exact reference f32 math: __fsub/__fmul/__fadd (no contraction), fminf.
// ---------------------------------------------------------------------------
__attribute__((amdgpu_waves_per_eu(4, 4)))
__global__ __launch_bounds__(1024) void fps_kernel(
    const float* __restrict__ xyz, int* __restrict__ fps_idx,
    float* __restrict__ new_xyz)
{
  const int b = blockIdx.x;
  const int t = threadIdx.x;
  const float* X = xyz + (size_t)b * NPTS * 3;

  __shared__ float4 s_mind4[4][1024];            // 64 KB, pack p = dists i=4p..4p+3
  __shared__ float wvv[16];                      // per-wave f32 max
  __shared__ unsigned long long s_packed;        // (g_bits<<32)|~origidx
  __shared__ float cbuf[3];

#define DECLP(i) float px##i, py##i, pz##i;
  PTS16(DECLP)
#undef DECLP

#define LOADP(i) { int j = t + (i << 10);  \
    px##i = X[3 * j + 0];                  \
    py##i = X[3 * j + 1];                  \
    pz##i = X[3 * j + 2]; }
  PTS16(LOADP)
#undef LOADP
  s_mind4[0][t] = make_float4(1e10f, 1e10f, 1e10f, 1e10f);
  s_mind4[1][t] = make_float4(1e10f, 1e10f, 1e10f, 1e10f);
  s_mind4[2][t] = make_float4(1e10f, 1e10f, 1e10f, 1e10f);
  s_mind4[3][t] = make_float4(1e10f, 1e10f, 1e10f, 1e10f);

  if (t == 0) { cbuf[0] = X[0]; cbuf[1] = X[1]; cbuf[2] = X[2]; s_packed = 0ull; }
  int far = 0;
  __syncthreads();

  for (int s = 0; s < NPOINT; ++s) {
    const float cx = cbuf[0], cy = cbuf[1], cz = cbuf[2];
    if (t == 0) {
      fps_idx[b * NPOINT + s] = far;
      float* o = new_xyz + ((size_t)b * NPOINT + s) * 3;
      o[0] = cx; o[1] = cy; o[2] = cz;
      s_packed = 0ull;                  // reset for this step's atomicMax
    }
    if (s == NPOINT - 1) break;

    // pin coords in VGPRs (blocks spill/remat; r9/r11-proven)
    asm volatile("" : "+v"(px0), "+v"(px1), "+v"(px2), "+v"(px3),
                      "+v"(px4), "+v"(px5), "+v"(px6), "+v"(px7),
                      "+v"(px8), "+v"(px9), "+v"(px10), "+v"(px11),
                      "+v"(px12), "+v"(px13), "+v"(px14), "+v"(px15));
    asm volatile("" : "+v"(py0), "+v"(py1), "+v"(py2), "+v"(py3),
                      "+v"(py4), "+v"(py5), "+v"(py6), "+v"(py7),
                      "+v"(py8), "+v"(py9), "+v"(py10), "+v"(py11),
                      "+v"(py12), "+v"(py13), "+v"(py14), "+v"(py15));
    asm volatile("" : "+v"(pz0), "+v"(pz1), "+v"(pz2), "+v"(pz3),
                      "+v"(pz4), "+v"(pz5), "+v"(pz6), "+v"(pz7),
                      "+v"(pz8), "+v"(pz9), "+v"(pz10), "+v"(pz11),
                      "+v"(pz12), "+v"(pz13), "+v"(pz14), "+v"(pz15));

    float mybest = -1.0f;
#define DIST(i) ({                                                       \
    float dx_ = __fsub_rn(px##i, cx);                                    \
    float dy_ = __fsub_rn(py##i, cy);                                    \
    float dz_ = __fsub_rn(pz##i, cz);                                    \
    __fadd_rn(__fadd_rn(__fmul_rn(dx_, dx_), __fmul_rn(dy_, dy_)),       \
              __fmul_rn(dz_, dz_)); })
#define PACKSTEP(p, i0, i1, i2, i3) {                                    \
    float4 dv = s_mind4[p][t];                                           \
    dv.x = fminf(dv.x, DIST(i0));                                        \
    dv.y = fminf(dv.y, DIST(i1));                                        \
    dv.z = fminf(dv.z, DIST(i2));                                        \
    dv.w = fminf(dv.w, DIST(i3));                                        \
    s_mind4[p][t] = dv;                                                  \
    mybest = fmaxf(mybest, fmaxf(fmaxf(dv.x, dv.y), fmaxf(dv.z, dv.w))); }
    PACKSTEP(0, 0, 1, 2, 3)
    PACKSTEP(1, 4, 5, 6, 7)
    PACKSTEP(2, 8, 9, 10, 11)
    PACKSTEP(3, 12, 13, 14, 15)
#undef PACKSTEP
#undef DIST

    // f32-only wave max
    float wmax = mybest;
#pragma unroll
    for (int off = 32; off >= 1; off >>= 1)
      wmax = fmaxf(wmax, __shfl_xor(wmax, off));
    if ((t & 63) == 0) wvv[t >> 6] = wmax;
    __syncthreads();   // B1

    // stage 2 (redundant, f32): 4x b128 broadcast + max tree
    float4 v0 = *(const float4*)&wvv[0];
    float4 v1 = *(const float4*)&wvv[4];
    float4 v2 = *(const float4*)&wvv[8];
    float4 v3 = *(const float4*)&wvv[12];
    float g = fmaxf(
        fmaxf(fmaxf(fmaxf(v0.x, v0.y), fmaxf(v0.z, v0.w)),
              fmaxf(fmaxf(v1.x, v1.y), fmaxf(v1.z, v1.w))),
        fmaxf(fmaxf(fmaxf(v2.x, v2.y), fmaxf(v2.z, v2.w)),
              fmaxf(fmaxf(v3.x, v3.y), fmaxf(v3.z, v3.w))));

    // winners (bit-exact; usually 1 thread): descending-overwrite scan
    if (mybest == g) {
      int kk = 16;
#pragma unroll
      for (int p = 3; p >= 0; --p) {
        float4 dv = s_mind4[p][t];
        if (dv.w == g) kk = 4 * p + 3;
        if (dv.z == g) kk = 4 * p + 2;
        if (dv.y == g) kk = 4 * p + 1;
        if (dv.x == g) kk = 4 * p + 0;
      }
      unsigned idx = (unsigned)(t + (kk << 10));
      unsigned long long pk =
          ((unsigned long long)__float_as_uint(g) << 32) | (unsigned)(~idx);
      atomicMax(&s_packed, pk);
    }
    __syncthreads();   // B2

    unsigned long long gp = s_packed;
    int widx = (int)(~(unsigned)(gp & 0xffffffffull)) & 0x3fff;
    far = widx;
    if (t == (widx & 1023)) {
      int c = widx >> 10;
#define OWNK(i) if (c == i) { cbuf[0] = px##i; cbuf[1] = py##i; cbuf[2] = pz##i; }
      PTS16(OWNK)
#undef OWNK
    }
    __syncthreads();   // B3
  }
}

// ---------------------------------------------------------------------------
// Kernel 2: exact 32-NN, 8 centroids per wave (r13).
// r11's 16-centroid version showed VGPR_Count=88 against ~130 live floats ->
// the allocator was spilling the queue arrays (same pathology as fps r1-r8;
// scratch is L2-resident so it never shows in FETCH_SIZE). Halving centroids
// per wave cuts live state to ~65 regs (under any grant) and doubles wave
// count (512 blocks -> 2 waves/SIMD TLP instead of 1).
// Same exact rounding + insertion semantics as the passing version.
// ---------------------------------------------------------------------------
__attribute__((amdgpu_waves_per_eu(2, 2)))
__global__ __launch_bounds__(256) void knn_kernel(
    const float* __restrict__ xyz, const float* __restrict__ new_xyz,
    int* __restrict__ knn_idx)
{
  const int lane = threadIdx.x & 63;
  const int wid  = threadIdx.x >> 6;
  const int gidbase = blockIdx.x * 32 + wid * 8;    // 8 centroids per wave
  const int b = gidbase / NPOINT;                   // uniform per block
  const float* X = xyz + (size_t)b * NPTS * 3;

  float cx[8], cy[8], cz[8];
#pragma unroll
  for (int c = 0; c < 8; ++c) {
    const float* p = new_xyz + (size_t)(gidbase + c) * 3;
    cx[c] = p[0]; cy[c] = p[1]; cz[c] = p[2];
  }

  float qd[8]; int qi[8]; float T[8];
#pragma unroll
  for (int c = 0; c < 8; ++c) { qd[c] = 3.4e38f; qi[c] = 0; T[c] = 3.4e38f; }

  for (int base = 0; base < NPTS; base += 64) {
    const int j = base + lane;
    const float x = X[3 * j + 0];
    const float y = X[3 * j + 1];
    const float z = X[3 * j + 2];
#pragma unroll
    for (int c = 0; c < 8; ++c) {
      float dx = __fsub_rn(x, cx[c]);
      float dy = __fsub_rn(y, cy[c]);
      float dz = __fsub_rn(z, cz[c]);
      float v  = __fadd_rn(__fadd_rn(__fmul_rn(dx, dx), __fmul_rn(dy, dy)),
                           __fmul_rn(dz, dz));
      unsigned long long m = __ballot(v < T[c]);
      while (m) {
        int bit = __ffsll(m) - 1;
        m &= m - 1;
        float vb = __shfl(v, bit);
        if (vb < T[c]) {                 // re-check: T shrinks as we insert
          int   jb = base + bit;
          float du = __shfl_up(qd[c], 1);
          int   iu = __shfl_up(qi[c], 1);
          bool c2 = (lane > 0) && (vb < du);
          bool c1 = vb < qd[c];
          qd[c] = c2 ? du : (c1 ? vb : qd[c]);
          qi[c] = c2 ? iu : (c1 ? jb : qi[c]);
          T[c] = __shfl(qd[c], 31);
        }
      }
    }
  }
#pragma unroll
  for (int c = 0; c < 8; ++c) {
    if (lane < 32) knn_idx[(size_t)(gidbase + c) * NSAMPLE + lane] = qi[c];
  }
}

// ---------------------------------------------------------------------------
// Kernel 3: gather + NeRF encoding + 3-layer MLP (f32) + max over k (r13).
// Layer 3 split into TWO sequential 32-column passes: the old single-pass
// version held a0[32]+a1[32] = 64 accumulator regs (+working ~90), above the
// allocator's grant -> scratch spill (L2-resident, invisible in FETCH).
// Each pass re-reads the cheap LDS activation broadcasts instead; peak live
// drops to ~70 regs. Math order per output column is unchanged
// (bit-identical results).
// ---------------------------------------------------------------------------
__attribute__((amdgpu_waves_per_eu(4, 4)))
__global__ __launch_bounds__(128) void mlp_kernel(
    const float* __restrict__ xyz, const float* __restrict__ features,
    const float* __restrict__ new_xyz, const int* __restrict__ knn_idx,
    const float* __restrict__ W1, const float* __restrict__ b1,
    const float* __restrict__ g1, const float* __restrict__ be1,
    const float* __restrict__ W2, const float* __restrict__ b2,
    const float* __restrict__ g2, const float* __restrict__ be2,
    const float* __restrict__ W3, const float* __restrict__ b3,
    float* __restrict__ out)
{
  const int g = blockIdx.x;
  const int b = g / NPOINT;
  const int t = threadIdx.x;

  __shared__ float bufT[128 * 36];
  __shared__ int   ki[32];
  __shared__ float cen[3];
  __shared__ float red[32][4][2];
  __shared__ float lnp[32][2];

  if (t < 32) ki[t] = knn_idx[(size_t)g * NSAMPLE + t];
  if (t < 3)  cen[t] = new_xyz[(size_t)g * 3 + t];
  __syncthreads();

  {
    int r = t & 31, cs = (t >> 5) << 4;
    const float* frow = features + ((size_t)b * NPTS + ki[r]) * CFEAT + cs;
#pragma unroll
    for (int u = 0; u < 4; ++u) {
      float4 f = *(const float4*)(frow + 4 * u);
      bufT[(cs + 4 * u + 0) * 36 + r] = f.x;
      bufT[(cs + 4 * u + 1) * 36 + r] = f.y;
      bufT[(cs + 4 * u + 2) * 36 + r] = f.z;
      bufT[(cs + 4 * u + 3) * 36 + r] = f.w;
    }
  }
  if (t < 32) {
    const float* p = xyz + ((size_t)b * NPTS + ki[t]) * 3;
    float rx = p[0] - cen[0];
    float ry = p[1] - cen[1];
    float rz = p[2] - cen[2];
#pragma unroll
    for (int l = 0; l < 10; ++l) {
      float sc = (float)(1 << l);
      float ax = rx * sc, ay = ry * sc, az = rz * sc;
      int base = (64 + l * 6) * 36 + t;
      bufT[base + 0 * 36] = __sinf(ax);
      bufT[base + 1 * 36] = __sinf(ay);
      bufT[base + 2 * 36] = __sinf(az);
      bufT[base + 3 * 36] = __cosf(ax);
      bufT[base + 4 * 36] = __cosf(ay);
      bufT[base + 5 * 36] = __cosf(az);
    }
  }
  __syncthreads();

  float acc[32];

  // ================= layer 1 =================
  {
    float bias = b1[t];
#pragma unroll
    for (int r = 0; r < 32; ++r) acc[r] = bias;
    for (int i = 0; i < DIN; ++i) {
      float w = W1[i * D1 + t];
      const float* hr = &bufT[i * 36];
#pragma unroll
      for (int r = 0; r < 32; ++r) acc[r] = fmaf(hr[r], w, acc[r]);
    }
  }
  {
    __syncthreads();
#pragma unroll
    for (int r = 0; r < 32; ++r) bufT[t * 36 + r] = acc[r];
    __syncthreads();
    {
      int r = t & 31, seg = t >> 5;
      float s = 0.f, ss = 0.f;
#pragma unroll
      for (int u = 0; u < 32; ++u) {
        float v = bufT[(seg * 32 + u) * 36 + r];
        s += v; ss = fmaf(v, v, ss);
      }
      red[r][seg][0] = s; red[r][seg][1] = ss;
    }
    __syncthreads();
    if (t < 32) {
      float s  = red[t][0][0] + red[t][1][0] + red[t][2][0] + red[t][3][0];
      float ss = red[t][0][1] + red[t][1][1] + red[t][2][1] + red[t][3][1];
      float m  = s * (1.0f / D1);
      float var = ss * (1.0f / D1) - m * m;
      lnp[t][0] = m;
      lnp[t][1] = rsqrtf(var + LN_EPS);
    }
    __syncthreads();
    float gg = g1[t], bb = be1[t];
#pragma unroll
    for (int r = 0; r < 32; ++r) {
      float v = (acc[r] - lnp[r][0]) * lnp[r][1];
      v = fmaf(v, gg, bb);
      bufT[t * 36 + r] = fmaxf(v, 0.f);
    }
    __syncthreads();
  }

  // ================= layer 2 =================
  {
    float bias = b2[t];
#pragma unroll
    for (int r = 0; r < 32; ++r) acc[r] = bias;
    for (int i = 0; i < D1; ++i) {
      float w = W2[i * D2 + t];
      const float* hr = &bufT[i * 36];
#pragma unroll
      for (int r = 0; r < 32; ++r) acc[r] = fmaf(hr[r], w, acc[r]);
    }
  }
  {
    __syncthreads();
#pragma unroll
    for (int r = 0; r < 32; ++r) bufT[t * 36 + r] = acc[r];
    __syncthreads();
    {
      int r = t & 31, seg = t >> 5;
      float s = 0.f, ss = 0.f;
#pragma unroll
      for (int u = 0; u < 32; ++u) {
        float v = bufT[(seg * 32 + u) * 36 + r];
        s += v; ss = fmaf(v, v, ss);
      }
      red[r][seg][0] = s; red[r][seg][1] = ss;
    }
    __syncthreads();
    if (t < 32) {
      float s  = red[t][0][0] + red[t][1][0] + red[t][2][0] + red[t][3][0];
      float ss = red[t][0][1] + red[t][1][1] + red[t][2][1] + red[t][3][1];
      float m  = s * (1.0f / D2);
      float var = ss * (1.0f / D2) - m * m;
      lnp[t][0] = m;
      lnp[t][1] = rsqrtf(var + LN_EPS);
    }
    __syncthreads();
    float gg = g2[t], bb = be2[t];
#pragma unroll
    for (int r = 0; r < 32; ++r) {
      float v = (acc[r] - lnp[r][0]) * lnp[r][1];
      v = fmaf(v, gg, bb);
      bufT[t * 36 + r] = fmaxf(v, 0.f);
    }
    __syncthreads();
  }

  // ============ layer 3 + max over k: two 32-reg passes ============
  float* of = out + (size_t)g * D3;
#pragma unroll 1
  for (int half = 0; half < 2; ++half) {
    int col = t + (half << 7);
    float a[32];
    float bias = b3[col];
#pragma unroll
    for (int r = 0; r < 32; ++r) a[r] = bias;
    for (int i = 0; i < D2; ++i) {
      float w = W3[i * D3 + col];
      const float* hr = &bufT[i * 36];
#pragma unroll
      for (int r = 0; r < 32; ++r) a[r] = fmaf(hr[r], w, a[r]);
    }
    float m0 = a[0];
#pragma unroll
    for (int r = 1; r < 32; ++r) m0 = fmaxf(m0, a[r]);
    of[col] = m0;
  }
}

// ---------------------------------------------------------------------------
extern "C" void kernel_launch(void* const* d_in, const int* in_sizes, int n_in,
                              void* d_out, int out_size, void* d_ws, size_t ws_size,
                              hipStream_t stream) {
  const float* xyz      = (const float*)d_in[0];
  const float* features = (const float*)d_in[1];
  const float* W1  = (const float*)d_in[2];
  const float* b1  = (const float*)d_in[3];
  const float* g1  = (const float*)d_in[4];
  const float* be1 = (const float*)d_in[5];
  const float* W2  = (const float*)d_in[6];
  const float* b2  = (const float*)d_in[7];
  const float* g2  = (const float*)d_in[8];
  const float* be2 = (const float*)d_in[9];
  const float* W3  = (const float*)d_in[10];
  const float* b3  = (const float*)d_in[11];

  float* new_xyz  = (float*)d_out;
  float* new_feat = (float*)d_out + (size_t)BATCH * NPOINT * 3;

  int* fps_idx = (int*)d_ws;
  int* knn_idx = fps_idx + BATCH * NPOINT;

  fps_kernel<<<dim3(BATCH), dim3(1024), 0, stream>>>(xyz, fps_idx, new_xyz);
  knn_kernel<<<dim3((BATCH * NPOINT) / 32), dim3(256), 0, stream>>>(xyz, new_xyz, knn_idx);
  mlp_kernel<<<dim3(BATCH * NPOINT), dim3(128), 0, stream>>>(
      xyz, features, new_xyz, knn_idx,
      W1, b1, g1, be1, W2, b2, g2, be2, W3, b3, new_feat);
}

// Round 14
// 5055.420 us; speedup vs baseline: 1.2443x; 1.1369x over previous
//
#include <hip/hip_runtime.h>
#include <cstdint>
#include <cstddef>

#define BATCH   8
#define NPTS    16384
#define CFEAT   64
#define NPOINT  2048
#define NSAMPLE 32
#define DIN     124
#define D1      128
#define D2      128
#define D3      256
#define LN_EPS  1e-5f

#define NFPS      8
#define NBLOCKS   256
#define KNN_ITEMS 128                   // 128 centroids per item (16 waves x 8)
#define MLP_ITEMS 2048                  // 8 centroids per item
#define TOT_ITEMS (KNN_ITEMS + MLP_ITEMS)

#define SB_BYTES   19872                // per-mlp-sub-block LDS region
#define SMEM_BYTES (8 * SB_BYTES)       // 158976 <= 160 KiB -> 1 block/CU

#define PTS16(F) F(0) F(1) F(2) F(3) F(4) F(5) F(6) F(7) \
                 F(8) F(9) F(10) F(11) F(12) F(13) F(14) F(15)

// ---------------------------------------------------------------------------
// Fused producer/consumer kernel. 256 blocks x 1024 thr, 1 block/CU.
//  - blocks 0..7: FPS (r11 structure verbatim, best measured 4.24 ms),
//    publishing prog[b] every 16 steps (release fence + agent atomic).
//  - blocks 8..255: workers; atomic FIFO queue of 128 knn items then 2048
//    mlp items. knn waves spin (relaxed agent poll + s_sleep, acquire fence
//    on wake) for their centroids; mlp items wait on per-chunk kflag set by
//    the chunk's last knn wave (acq_rel counter). fps never waits; knn waits
//    only on fps; mlp only on knn; all blocks resident -> deadlock-free.
// All selection math bit-identical to r13 (passing, absmax 0.0156).
// ---------------------------------------------------------------------------
__attribute__((amdgpu_waves_per_eu(4, 4)))
__global__ __launch_bounds__(1024) void fused_kernel(
    const float* __restrict__ xyz, const float* __restrict__ features,
    const float* __restrict__ W1, const float* __restrict__ b1,
    const float* __restrict__ g1, const float* __restrict__ be1,
    const float* __restrict__ W2, const float* __restrict__ b2,
    const float* __restrict__ g2, const float* __restrict__ be2,
    const float* __restrict__ W3, const float* __restrict__ b3,
    int* __restrict__ knn_idx,
    unsigned* __restrict__ qhead, int* __restrict__ prog,
    unsigned* __restrict__ kcnt, unsigned* __restrict__ kflag,
    float* __restrict__ new_xyz, float* __restrict__ out)
{
  __shared__ __align__(16) unsigned char smem[SMEM_BYTES];
  __shared__ unsigned s_item;
  const int t = threadIdx.x;

  // ========================= FPS role (blocks 0..7) =========================
  if (blockIdx.x < NFPS) {
    const int b = blockIdx.x;
    const float* X = xyz + (size_t)b * NPTS * 3;

    float4 (*s_mind4)[1024] = reinterpret_cast<float4(*)[1024]>(smem);
    float* wvv = (float*)(smem + 65536);
    unsigned long long* s_packed = (unsigned long long*)(smem + 65600);
    float* cbuf = (float*)(smem + 65616);

#define DECLP(i) float px##i, py##i, pz##i;
    PTS16(DECLP)
#undef DECLP
#define LOADP(i) { int j = t + (i << 10);  \
    px##i = X[3 * j + 0];                  \
    py##i = X[3 * j + 1];                  \
    pz##i = X[3 * j + 2]; }
    PTS16(LOADP)
#undef LOADP
    s_mind4[0][t] = make_float4(1e10f, 1e10f, 1e10f, 1e10f);
    s_mind4[1][t] = make_float4(1e10f, 1e10f, 1e10f, 1e10f);
    s_mind4[2][t] = make_float4(1e10f, 1e10f, 1e10f, 1e10f);
    s_mind4[3][t] = make_float4(1e10f, 1e10f, 1e10f, 1e10f);

    if (t == 0) { cbuf[0] = X[0]; cbuf[1] = X[1]; cbuf[2] = X[2]; *s_packed = 0ull; }
    __syncthreads();

    for (int s = 0; s < NPOINT; ++s) {
      const float cx = cbuf[0], cy = cbuf[1], cz = cbuf[2];
      if (t == 0) {
        float* o = new_xyz + ((size_t)b * NPOINT + s) * 3;
        o[0] = cx; o[1] = cy; o[2] = cz;
        *s_packed = 0ull;
        if (((s + 1) & 15) == 0) {   // publish every 16 steps (incl. s=2047)
          __builtin_amdgcn_fence(__ATOMIC_RELEASE, "agent");
          __hip_atomic_store(&prog[b], s + 1, __ATOMIC_RELAXED,
                             __HIP_MEMORY_SCOPE_AGENT);
        }
      }
      if (s == NPOINT - 1) break;

      asm volatile("" : "+v"(px0), "+v"(px1), "+v"(px2), "+v"(px3),
                        "+v"(px4), "+v"(px5), "+v"(px6), "+v"(px7),
                        "+v"(px8), "+v"(px9), "+v"(px10), "+v"(px11),
                        "+v"(px12), "+v"(px13), "+v"(px14), "+v"(px15));
      asm volatile("" : "+v"(py0), "+v"(py1), "+v"(py2), "+v"(py3),
                        "+v"(py4), "+v"(py5), "+v"(py6), "+v"(py7),
                        "+v"(py8), "+v"(py9), "+v"(py10), "+v"(py11),
                        "+v"(py12), "+v"(py13), "+v"(py14), "+v"(py15));
      asm volatile("" : "+v"(pz0), "+v"(pz1), "+v"(pz2), "+v"(pz3),
                        "+v"(pz4), "+v"(pz5), "+v"(pz6), "+v"(pz7),
                        "+v"(pz8), "+v"(pz9), "+v"(pz10), "+v"(pz11),
                        "+v"(pz12), "+v"(pz13), "+v"(pz14), "+v"(pz15));

      float mybest = -1.0f;
#define DIST(i) ({                                                       \
    float dx_ = __fsub_rn(px##i, cx);                                    \
    float dy_ = __fsub_rn(py##i, cy);                                    \
    float dz_ = __fsub_rn(pz##i, cz);                                    \
    __fadd_rn(__fadd_rn(__fmul_rn(dx_, dx_), __fmul_rn(dy_, dy_)),       \
              __fmul_rn(dz_, dz_)); })
#define PACKSTEP(p, i0, i1, i2, i3) {                                    \
    float4 dv = s_mind4[p][t];                                           \
    dv.x = fminf(dv.x, DIST(i0));                                        \
    dv.y = fminf(dv.y, DIST(i1));                                        \
    dv.z = fminf(dv.z, DIST(i2));                                        \
    dv.w = fminf(dv.w, DIST(i3));                                        \
    s_mind4[p][t] = dv;                                                  \
    mybest = fmaxf(mybest, fmaxf(fmaxf(dv.x, dv.y), fmaxf(dv.z, dv.w))); }
      PACKSTEP(0, 0, 1, 2, 3)
      PACKSTEP(1, 4, 5, 6, 7)
      PACKSTEP(2, 8, 9, 10, 11)
      PACKSTEP(3, 12, 13, 14, 15)
#undef PACKSTEP
#undef DIST

      float wmax = mybest;
#pragma unroll
      for (int off = 32; off >= 1; off >>= 1)
        wmax = fmaxf(wmax, __shfl_xor(wmax, off));
      if ((t & 63) == 0) wvv[t >> 6] = wmax;
      __syncthreads();   // B1

      float4 v0 = *(const float4*)&wvv[0];
      float4 v1 = *(const float4*)&wvv[4];
      float4 v2 = *(const float4*)&wvv[8];
      float4 v3 = *(const float4*)&wvv[12];
      float g = fmaxf(
          fmaxf(fmaxf(fmaxf(v0.x, v0.y), fmaxf(v0.z, v0.w)),
                fmaxf(fmaxf(v1.x, v1.y), fmaxf(v1.z, v1.w))),
          fmaxf(fmaxf(fmaxf(v2.x, v2.y), fmaxf(v2.z, v2.w)),
                fmaxf(fmaxf(v3.x, v3.y), fmaxf(v3.z, v3.w))));

      if (mybest == g) {
        int kk = 16;
#pragma unroll
        for (int p = 3; p >= 0; --p) {
          float4 dv = s_mind4[p][t];
          if (dv.w == g) kk = 4 * p + 3;
          if (dv.z == g) kk = 4 * p + 2;
          if (dv.y == g) kk = 4 * p + 1;
          if (dv.x == g) kk = 4 * p + 0;
        }
        unsigned idx = (unsigned)(t + (kk << 10));
        unsigned long long pk =
            ((unsigned long long)__float_as_uint(g) << 32) | (unsigned)(~idx);
        atomicMax(s_packed, pk);
      }
      __syncthreads();   // B2

      unsigned long long gp = *s_packed;
      int widx = (int)(~(unsigned)(gp & 0xffffffffull)) & 0x3fff;
      if (t == (widx & 1023)) {
        int c = widx >> 10;
#define OWNK(i) if (c == i) { cbuf[0] = px##i; cbuf[1] = py##i; cbuf[2] = pz##i; }
        PTS16(OWNK)
#undef OWNK
      }
      __syncthreads();   // B3
    }
    return;
  }

  // ========================= worker role (blocks 8..255) ====================
  for (;;) {
    __syncthreads();
    if (t == 0)
      s_item = __hip_atomic_fetch_add(qhead, 1u, __ATOMIC_RELAXED,
                                      __HIP_MEMORY_SCOPE_AGENT);
    __syncthreads();
    unsigned item = s_item;
    if (item >= TOT_ITEMS) return;

    if (item < KNN_ITEMS) {
      // ---------------- knn item: 128 centroids, 16 waves x 8 --------------
      const int k = (int)item;
      const int b = k >> 4;                    // 16 chunks per batch
      const int chunk = k & 15;
      const int lane = t & 63;
      const int wid  = t >> 6;
      const int gidbase = b * NPOINT + chunk * 128 + wid * 8;
      const int need = chunk * 128 + wid * 8 + 8;
      const float* X = xyz + (size_t)b * NPTS * 3;

      if (lane == 0) {
        while (__hip_atomic_load(&prog[b], __ATOMIC_RELAXED,
                                 __HIP_MEMORY_SCOPE_AGENT) < need)
          __builtin_amdgcn_s_sleep(2);
      }
      __builtin_amdgcn_fence(__ATOMIC_ACQUIRE, "agent");

      float cx[8], cy[8], cz[8];
#pragma unroll
      for (int c = 0; c < 8; ++c) {
        const float* p = new_xyz + (size_t)(gidbase + c) * 3;
        cx[c] = p[0]; cy[c] = p[1]; cz[c] = p[2];
      }
      float qd[8]; int qi[8]; float T[8];
#pragma unroll
      for (int c = 0; c < 8; ++c) { qd[c] = 3.4e38f; qi[c] = 0; T[c] = 3.4e38f; }

      for (int base = 0; base < NPTS; base += 64) {
        const int j = base + lane;
        const float x = X[3 * j + 0];
        const float y = X[3 * j + 1];
        const float z = X[3 * j + 2];
#pragma unroll
        for (int c = 0; c < 8; ++c) {
          float dx = __fsub_rn(x, cx[c]);
          float dy = __fsub_rn(y, cy[c]);
          float dz = __fsub_rn(z, cz[c]);
          float v  = __fadd_rn(__fadd_rn(__fmul_rn(dx, dx), __fmul_rn(dy, dy)),
                               __fmul_rn(dz, dz));
          unsigned long long m = __ballot(v < T[c]);
          while (m) {
            int bit = __ffsll(m) - 1;
            m &= m - 1;
            float vb = __shfl(v, bit);
            if (vb < T[c]) {
              int   jb = base + bit;
              float du = __shfl_up(qd[c], 1);
              int   iu = __shfl_up(qi[c], 1);
              bool c2 = (lane > 0) && (vb < du);
              bool c1 = vb < qd[c];
              qd[c] = c2 ? du : (c1 ? vb : qd[c]);
              qi[c] = c2 ? iu : (c1 ? jb : qi[c]);
              T[c] = __shfl(qd[c], 31);
            }
          }
        }
      }
#pragma unroll
      for (int c = 0; c < 8; ++c) {
        if (lane < 32) knn_idx[(size_t)(gidbase + c) * NSAMPLE + lane] = qi[c];
      }
      __builtin_amdgcn_fence(__ATOMIC_RELEASE, "agent");
      if (lane == 0) {
        unsigned d = __hip_atomic_fetch_add(&kcnt[k], 1u, __ATOMIC_ACQ_REL,
                                            __HIP_MEMORY_SCOPE_AGENT);
        if (d == 15u)
          __hip_atomic_store(&kflag[k], 1u, __ATOMIC_RELEASE,
                             __HIP_MEMORY_SCOPE_AGENT);
      }
    } else {
      // ---------------- mlp item: 8 centroids, 8 x 128-thr sub-blocks ------
      const int m = (int)(item - KNN_ITEMS);
      const int gbase = m << 3;
      const int b = gbase / NPOINT;
      const int sb = t >> 7;
      const int t127 = t & 127;
      const int g = gbase + sb;

      if (t == 0) {
        while (__hip_atomic_load(&kflag[m >> 4], __ATOMIC_RELAXED,
                                 __HIP_MEMORY_SCOPE_AGENT) == 0u)
          __builtin_amdgcn_s_sleep(2);
      }
      __syncthreads();
      __builtin_amdgcn_fence(__ATOMIC_ACQUIRE, "agent");

      unsigned char* base_ = smem + sb * SB_BYTES;
      float* bufT = (float*)base_;                         // 128*36 floats
      float (*red)[4][2] = (float(*)[4][2])(base_ + 18432);
      float (*lnp)[2]    = (float(*)[2])(base_ + 19456);
      int*   ki          = (int*)(base_ + 19712);
      float* cen         = (float*)(base_ + 19840);

      if (t127 < 32) ki[t127] = knn_idx[(size_t)g * NSAMPLE + t127];
      if (t127 < 3)  cen[t127] = new_xyz[(size_t)g * 3 + t127];
      __syncthreads();

      {
        int r = t127 & 31, cs = (t127 >> 5) << 4;
        const float* frow = features + ((size_t)b * NPTS + ki[r]) * CFEAT + cs;
#pragma unroll
        for (int u = 0; u < 4; ++u) {
          float4 f = *(const float4*)(frow + 4 * u);
          bufT[(cs + 4 * u + 0) * 36 + r] = f.x;
          bufT[(cs + 4 * u + 1) * 36 + r] = f.y;
          bufT[(cs + 4 * u + 2) * 36 + r] = f.z;
          bufT[(cs + 4 * u + 3) * 36 + r] = f.w;
        }
      }
      if (t127 < 32) {
        const float* p = xyz + ((size_t)b * NPTS + ki[t127]) * 3;
        float rx = p[0] - cen[0];
        float ry = p[1] - cen[1];
        float rz = p[2] - cen[2];
#pragma unroll
        for (int l = 0; l < 10; ++l) {
          float sc = (float)(1 << l);
          float ax = rx * sc, ay = ry * sc, az = rz * sc;
          int bbi = (64 + l * 6) * 36 + t127;
          bufT[bbi + 0 * 36] = __sinf(ax);
          bufT[bbi + 1 * 36] = __sinf(ay);
          bufT[bbi + 2 * 36] = __sinf(az);
          bufT[bbi + 3 * 36] = __cosf(ax);
          bufT[bbi + 4 * 36] = __cosf(ay);
          bufT[bbi + 5 * 36] = __cosf(az);
        }
      }
      __syncthreads();

      float acc[32];
      // ---- layer 1 ----
      {
        float bias = b1[t127];
#pragma unroll
        for (int r = 0; r < 32; ++r) acc[r] = bias;
        for (int i = 0; i < DIN; ++i) {
          float w = W1[i * D1 + t127];
          const float* hr = &bufT[i * 36];
#pragma unroll
          for (int r = 0; r < 32; ++r) acc[r] = fmaf(hr[r], w, acc[r]);
        }
      }
      {
        __syncthreads();
#pragma unroll
        for (int r = 0; r < 32; ++r) bufT[t127 * 36 + r] = acc[r];
        __syncthreads();
        {
          int r = t127 & 31, seg = t127 >> 5;
          float s = 0.f, ss = 0.f;
#pragma unroll
          for (int u = 0; u < 32; ++u) {
            float v = bufT[(seg * 32 + u) * 36 + r];
            s += v; ss = fmaf(v, v, ss);
          }
          red[r][seg][0] = s; red[r][seg][1] = ss;
        }
        __syncthreads();
        if (t127 < 32) {
          float s  = red[t127][0][0] + red[t127][1][0] + red[t127][2][0] + red[t127][3][0];
          float ss = red[t127][0][1] + red[t127][1][1] + red[t127][2][1] + red[t127][3][1];
          float mm = s * (1.0f / D1);
          float var = ss * (1.0f / D1) - mm * mm;
          lnp[t127][0] = mm;
          lnp[t127][1] = rsqrtf(var + LN_EPS);
        }
        __syncthreads();
        float gg = g1[t127], bb = be1[t127];
#pragma unroll
        for (int r = 0; r < 32; ++r) {
          float v = (acc[r] - lnp[r][0]) * lnp[r][1];
          v = fmaf(v, gg, bb);
          bufT[t127 * 36 + r] = fmaxf(v, 0.f);
        }
        __syncthreads();
      }
      // ---- layer 2 ----
      {
        float bias = b2[t127];
#pragma unroll
        for (int r = 0; r < 32; ++r) acc[r] = bias;
        for (int i = 0; i < D1; ++i) {
          float w = W2[i * D2 + t127];
          const float* hr = &bufT[i * 36];
#pragma unroll
          for (int r = 0; r < 32; ++r) acc[r] = fmaf(hr[r], w, acc[r]);
        }
      }
      {
        __syncthreads();
#pragma unroll
        for (int r = 0; r < 32; ++r) bufT[t127 * 36 + r] = acc[r];
        __syncthreads();
        {
          int r = t127 & 31, seg = t127 >> 5;
          float s = 0.f, ss = 0.f;
#pragma unroll
          for (int u = 0; u < 32; ++u) {
            float v = bufT[(seg * 32 + u) * 36 + r];
            s += v; ss = fmaf(v, v, ss);
          }
          red[r][seg][0] = s; red[r][seg][1] = ss;
        }
        __syncthreads();
        if (t127 < 32) {
          float s  = red[t127][0][0] + red[t127][1][0] + red[t127][2][0] + red[t127][3][0];
          float ss = red[t127][0][1] + red[t127][1][1] + red[t127][2][1] + red[t127][3][1];
          float mm = s * (1.0f / D2);
          float var = ss * (1.0f / D2) - mm * mm;
          lnp[t127][0] = mm;
          lnp[t127][1] = rsqrtf(var + LN_EPS);
        }
        __syncthreads();
        float gg = g2[t127], bb = be2[t127];
#pragma unroll
        for (int r = 0; r < 32; ++r) {
          float v = (acc[r] - lnp[r][0]) * lnp[r][1];
          v = fmaf(v, gg, bb);
          bufT[t127 * 36 + r] = fmaxf(v, 0.f);
        }
        __syncthreads();
      }
      // ---- layer 3 + max over k: two 32-reg passes ----
      float* of = out + (size_t)g * D3;
#pragma unroll 1
      for (int half = 0; half < 2; ++half) {
        int col = t127 + (half << 7);
        float a[32];
        float bias = b3[col];
#pragma unroll
        for (int r = 0; r < 32; ++r) a[r] = bias;
        for (int i = 0; i < D2; ++i) {
          float w = W3[i * D3 + col];
          const float* hr = &bufT[i * 36];
#pragma unroll
          for (int r = 0; r < 32; ++r) a[r] = fmaf(hr[r], w, a[r]);
        }
        float m0 = a[0];
#pragma unroll
        for (int r = 1; r < 32; ++r) m0 = fmaxf(m0, a[r]);
        of[col] = m0;
      }
      __syncthreads();   // sub-blocks done before LDS reuse by next item
    }
  }
}

// ---------------------------------------------------------------------------
extern "C" void kernel_launch(void* const* d_in, const int* in_sizes, int n_in,
                              void* d_out, int out_size, void* d_ws, size_t ws_size,
                              hipStream_t stream) {
  const float* xyz      = (const float*)d_in[0];
  const float* features = (const float*)d_in[1];
  const float* W1  = (const float*)d_in[2];
  const float* b1  = (const float*)d_in[3];
  const float* g1  = (const float*)d_in[4];
  const float* be1 = (const float*)d_in[5];
  const float* W2  = (const float*)d_in[6];
  const float* b2  = (const float*)d_in[7];
  const float* g2  = (const float*)d_in[8];
  const float* be2 = (const float*)d_in[9];
  const float* W3  = (const float*)d_in[10];
  const float* b3  = (const float*)d_in[11];

  float* new_xyz  = (float*)d_out;
  float* new_feat = (float*)d_out + (size_t)BATCH * NPOINT * 3;

  int* knn_idx = (int*)d_ws;                                    // 2 MB
  unsigned char* ctl = (unsigned char*)d_ws +
                       (size_t)BATCH * NPOINT * NSAMPLE * 4;
  // ctl layout: [0] qhead u32 | [64] prog int[8] | [128] kcnt u32[128]
  //             | [1024] kflag u32[128] | total < 2048
  unsigned* qhead = (unsigned*)ctl;
  int*      prog  = (int*)(ctl + 64);
  unsigned* kcnt  = (unsigned*)(ctl + 128);
  unsigned* kflag = (unsigned*)(ctl + 1024);

  hipMemsetAsync(ctl, 0, 2048, stream);
  fused_kernel<<<dim3(NBLOCKS), dim3(1024), 0, stream>>>(
      xyz, features, W1, b1, g1, be1, W2, b2, g2, be2, W3, b3,
      knn_idx, qhead, prog, kcnt, kflag, new_xyz, new_feat);
}